// Round 10
// baseline (881.594 us; speedup 1.0000x reference)
//
#include <hip/hip_runtime.h>

#define NEG_GAT 0.2f
#define NEG_ACT 0.01f
#define BN_EPS 1e-5f

__device__ __forceinline__ float wred64(float v) {
  #pragma unroll
  for (int o = 32; o; o >>= 1) v += __shfl_down(v, o);
  return v;
}
__device__ __forceinline__ int wredi64(int v) {
  #pragma unroll
  for (int o = 32; o; o >>= 1) v += __shfl_down(v, o);
  return v;
}
// inclusive wave scan (64 lanes)
__device__ __forceinline__ int wscani(int x, int lane) {
  #pragma unroll
  for (int off = 1; off < 64; off <<= 1) {
    int t = __shfl_up(x, off);
    if (lane >= off) x += t;
  }
  return x;
}

// ---- precompute all small constants:
//  ae2[8]   : We@ae per set                (2 scalars x {L1,G1,L2,G2})
//  l1c[8]   : W1@as, W1@ad per layer-1 set (2+2 scalars x {L,G})
//  was2[256]: W2@as2, W2@ad2 per layer-2 set (64+64 x {L,G})
__global__ void k_prep(const float* WL1, const float* WeL1, const float* asL1,
                       const float* adL1, const float* aeL1,
                       const float* WG1, const float* WeG1, const float* asG1,
                       const float* adG1, const float* aeG1,
                       const float* WL2, const float* WeL2, const float* asL2,
                       const float* adL2, const float* aeL2,
                       const float* WG2, const float* WeG2, const float* asG2,
                       const float* adG2, const float* aeG2,
                       float* ae2, float* l1c, float* was2) {
  int lane = threadIdx.x;  // 64 threads
  const float* We[4] = {WeL1, WeG1, WeL2, WeG2};
  const float* ae[4] = {aeL1, aeG1, aeL2, aeG2};
  for (int s = 0; s < 4; s++) {
    float v0 = wred64(We[s][lane] * ae[s][lane]);
    float v1 = wred64(We[s][64 + lane] * ae[s][lane]);
    if (lane == 0) { ae2[2 * s] = v0; ae2[2 * s + 1] = v1; }
  }
  const float* W1[2] = {WL1, WG1};
  const float* a1s[2] = {asL1, asG1};
  const float* a1d[2] = {adL1, adG1};
  for (int t = 0; t < 2; t++) {
    float ws0 = wred64(W1[t][lane] * a1s[t][lane]);
    float ws1 = wred64(W1[t][64 + lane] * a1s[t][lane]);
    float wd0 = wred64(W1[t][lane] * a1d[t][lane]);
    float wd1 = wred64(W1[t][64 + lane] * a1d[t][lane]);
    if (lane == 0) {
      l1c[4 * t + 0] = ws0; l1c[4 * t + 1] = ws1;
      l1c[4 * t + 2] = wd0; l1c[4 * t + 3] = wd1;
    }
  }
  const float* W2[2] = {WL2, WG2};
  const float* a2s[2] = {asL2, asG2};
  const float* a2d[2] = {adL2, adG2};
  for (int t = 0; t < 2; t++) {
    float ss = 0.f, sd = 0.f;
    for (int j = 0; j < 64; j++) {
      float w = W2[t][lane * 64 + j];
      ss += w * a2s[t][j];
      sd += w * a2d[t][j];
    }
    was2[(2 * t) * 64 + lane] = ss;       // @as
    was2[(2 * t + 1) * 64 + lane] = sd;   // @ad
  }
}

// ---- edge_attr column sums (for mean fill of self-loop attrs) ----
__global__ void __launch_bounds__(256)
k_eamean(const float* __restrict__ eattr, float* acc, int E) {
  int i = blockIdx.x * blockDim.x + threadIdx.x;
  float s0 = 0.f, s1 = 0.f;
  for (int e = i; e < E; e += gridDim.x * blockDim.x) {
    float2 v = ((const float2*)eattr)[e];
    s0 += v.x; s1 += v.y;
  }
  s0 = wred64(s0);
  s1 = wred64(s1);
  if ((threadIdx.x & 63) == 0) {
    atomicAdd(&acc[0], s0);
    atomicAdd(&acc[1], s1);
  }
}

// ---- CSR 1: in-degree histogram ----
__global__ void __launch_bounds__(256)
k_hist(const int* __restrict__ ei, int* __restrict__ cnt, int E) {
  int e = blockIdx.x * blockDim.x + threadIdx.x;
  if (e < E) atomicAdd(&cnt[ei[E + e]], 1);
}

// ---- CSR 2a: per-chunk (1024-elem) sums ----
__global__ void __launch_bounds__(256)
k_scanA(const int* __restrict__ cnt, int* __restrict__ bsum, int N) {
  __shared__ int wsum[4];
  int tid = threadIdx.x, lane = tid & 63, wid = tid >> 6;
  int base = blockIdx.x * 1024 + tid * 4;
  int t = 0;
  if (base + 3 < N) {
    int4 q = *(const int4*)(cnt + base);
    t = q.x + q.y + q.z + q.w;
  } else {
    if (base < N) t += cnt[base];
    if (base + 1 < N) t += cnt[base + 1];
    if (base + 2 < N) t += cnt[base + 2];
    if (base + 3 < N) t += cnt[base + 3];
  }
  t = wredi64(t);
  if (lane == 0) wsum[wid] = t;
  __syncthreads();
  if (tid == 0) bsum[blockIdx.x] = wsum[0] + wsum[1] + wsum[2] + wsum[3];
}

// ---- CSR 2b: exclusive scan of chunk sums (nb <= 1024); also offs[N]=E ----
__global__ void __launch_bounds__(1024)
k_scanB(int* __restrict__ bsum, int* __restrict__ offs, int nb, int E, int N) {
  __shared__ int wsum[16];
  int tid = threadIdx.x, lane = tid & 63, wid = tid >> 6;
  int v = (tid < nb) ? bsum[tid] : 0;
  int x = wscani(v, lane);
  if (lane == 63) wsum[wid] = x;
  __syncthreads();
  if (wid == 0) {
    int w = (lane < 16) ? wsum[lane] : 0;
    w = wscani(w, lane);
    if (lane < 16) wsum[lane] = w;
  }
  __syncthreads();
  int incl = x + (wid ? wsum[wid - 1] : 0);
  if (tid < nb) bsum[tid] = incl - v;   // exclusive
  if (tid == 0) offs[N] = E;
}

// ---- CSR 2c: chunk-local exclusive scan + chunk base -> offs, cur ----
__global__ void __launch_bounds__(256)
k_scanC(const int* __restrict__ cnt, const int* __restrict__ bsum,
        int* __restrict__ offs, int* __restrict__ cur, int N) {
  __shared__ int wsum[4];
  int tid = threadIdx.x, lane = tid & 63, wid = tid >> 6;
  int base = blockIdx.x * 1024 + tid * 4;
  int v0 = 0, v1 = 0, v2 = 0, v3 = 0;
  if (base + 3 < N) {
    int4 q = *(const int4*)(cnt + base);
    v0 = q.x; v1 = q.y; v2 = q.z; v3 = q.w;
  } else {
    if (base < N) v0 = cnt[base];
    if (base + 1 < N) v1 = cnt[base + 1];
    if (base + 2 < N) v2 = cnt[base + 2];
    if (base + 3 < N) v3 = cnt[base + 3];
  }
  int t = v0 + v1 + v2 + v3;
  int incl = wscani(t, lane);
  int exclT = incl - t;
  if (lane == 63) wsum[wid] = incl;
  __syncthreads();
  int wb = 0;
  if (wid > 0) wb += wsum[0];
  if (wid > 1) wb += wsum[1];
  if (wid > 2) wb += wsum[2];
  int eb = bsum[blockIdx.x] + wb + exclT;
  if (base < N)     { offs[base] = eb;           cur[base] = eb; }
  if (base + 1 < N) { int u = eb + v0;           offs[base + 1] = u; cur[base + 1] = u; }
  if (base + 2 < N) { int u = eb + v0 + v1;      offs[base + 2] = u; cur[base + 2] = u; }
  if (base + 3 < N) { int u = eb + v0 + v1 + v2; offs[base + 3] = u; cur[base + 3] = u; }
}

// ---- layer1 node features: h = x@W; alphas via precomputed W@a (2 FMAs) ----
// (runs BEFORE k_fill so layer-1 alpha_src can be folded into edge records)
__global__ void __launch_bounds__(256)
k_node1(const float* __restrict__ x,
        const float* __restrict__ WL, const float* __restrict__ WG,
        const float* __restrict__ l1c,
        float* __restrict__ hL, float* __restrict__ hG,
        float* asL, float* adL, float* asG, float* adG, int N) {
  int idx = blockIdx.x * blockDim.x + threadIdx.x;
  int n = idx >> 6, lane = idx & 63;
  if (n >= N) return;
  float2 xv = ((const float2*)x)[n];
  hL[(size_t)n * 64 + lane] = xv.x * WL[lane] + xv.y * WL[64 + lane];
  hG[(size_t)n * 64 + lane] = xv.x * WG[lane] + xv.y * WG[64 + lane];
  if (lane == 0) {
    asL[n] = xv.x * l1c[0] + xv.y * l1c[1];
    adL[n] = xv.x * l1c[2] + xv.y * l1c[3];
    asG[n] = xv.x * l1c[4] + xv.y * l1c[5];
    adG[n] = xv.x * l1c[6] + xv.y * l1c[7];
  }
}

// ---- CSR 3: fill packed (src, as1[src]+et1, et2, mask) records, dst-sorted ----
__global__ void __launch_bounds__(256)
k_fill(const int* __restrict__ ei, const float* __restrict__ eattr,
       const int* __restrict__ mask, const float* __restrict__ ae2,
       const float* __restrict__ asL1, const float* __restrict__ asG1,
       int* __restrict__ cur, int4* __restrict__ edg, int E) {
  int e = blockIdx.x * blockDim.x + threadIdx.x;
  if (e >= E) return;
  int s = ei[e], d = ei[E + e];
  int m = mask[d];
  float2 ea = ((const float2*)eattr)[e];
  float as1 = m ? asG1[s] : asL1[s];
  float t1 = as1 + ea.x * (m ? ae2[2] : ae2[0]) + ea.y * (m ? ae2[3] : ae2[1]);
  float t2 =       ea.x * (m ? ae2[6] : ae2[4]) + ea.y * (m ? ae2[7] : ae2[5]);
  int j = atomicAdd(&cur[d], 1);
  edg[j] = make_int4(s, __float_as_int(t1), __float_as_int(t2), m);
}

// ---- refill pass (after k_node2): .y <- as2[src] + et2, so layer 2's gather
//      loop matches layer 1's 2-stream form. Thread-per-edge, streaming. ----
__global__ void __launch_bounds__(256)
k_refill(const float* __restrict__ asL2, const float* __restrict__ asG2,
         int4* __restrict__ edg, int E) {
  int j = blockIdx.x * blockDim.x + threadIdx.x;
  if (j >= E) return;
  int4 v = edg[j];
  float as2 = (v.w ? asG2 : asL2)[v.x];
  edg[j].y = __float_as_int(as2 + __int_as_float(v.z));
}

// ---- GAT row aggregation (wave-per-dst, registers only, 2 streams/edge).
//      Max-subtraction dropped: |logit| <= ~6 by construction; exp(m) cancels
//      exactly in coef = ex/denom. logit = rec.y + ad (alpha_src prefolded). ----
__device__ __forceinline__ float gat_row(
    int n, int lane, int m,
    const int* __restrict__ offs, const int4* __restrict__ edg,
    const float* __restrict__ hL, const float* __restrict__ hG,
    const float* __restrict__ asL, const float* __restrict__ adL,
    const float* __restrict__ asG, const float* __restrict__ adG,
    const float* __restrict__ ae2, const float* __restrict__ eacc, float invE) {
  const float* as_p = m ? asG : asL;
  const float* h_p  = m ? hG  : hL;
  float ad = (m ? adG : adL)[n];
  float k0 = m ? ae2[2] : ae2[0];
  float k1 = m ? ae2[3] : ae2[1];
  // self loop (ea = column means)
  float lg = as_p[n] + ad + (eacc[0] * invE) * k0 + (eacc[1] * invE) * k1;
  lg = lg >= 0.f ? lg : NEG_GAT * lg;
  float ex = __expf(lg);
  float denom = ex;
  float acc = ex * h_p[(size_t)n * 64 + lane];
  int j = offs[n], end = offs[n + 1];
  for (; j + 4 <= end; j += 4) {   // 4-wide software pipeline
    int4 v0 = edg[j], v1 = edg[j + 1], v2 = edg[j + 2], v3 = edg[j + 3];
    float h0 = h_p[(size_t)v0.x * 64 + lane];
    float h1 = h_p[(size_t)v1.x * 64 + lane];
    float h2 = h_p[(size_t)v2.x * 64 + lane];
    float h3 = h_p[(size_t)v3.x * 64 + lane];
    float l0 = __int_as_float(v0.y) + ad;
    float l1 = __int_as_float(v1.y) + ad;
    float l2 = __int_as_float(v2.y) + ad;
    float l3 = __int_as_float(v3.y) + ad;
    l0 = l0 >= 0.f ? l0 : NEG_GAT * l0;
    l1 = l1 >= 0.f ? l1 : NEG_GAT * l1;
    l2 = l2 >= 0.f ? l2 : NEG_GAT * l2;
    l3 = l3 >= 0.f ? l3 : NEG_GAT * l3;
    float e0 = __expf(l0), e1 = __expf(l1), e2 = __expf(l2), e3 = __expf(l3);
    denom += (e0 + e1) + (e2 + e3);
    acc = fmaf(e0, h0, acc);
    acc = fmaf(e1, h1, acc);
    acc = fmaf(e2, h2, acc);
    acc = fmaf(e3, h3, acc);
  }
  for (; j < end; j++) {
    int4 v = edg[j];
    float hv = h_p[(size_t)v.x * 64 + lane];
    float l = __int_as_float(v.y) + ad;
    l = l >= 0.f ? l : NEG_GAT * l;
    float e = __expf(l);
    denom += e;
    acc = fmaf(e, hv, acc);
  }
  return acc / denom;
}

// ---- layer 1: GAT -> C = out + bias ----
__global__ void __launch_bounds__(256)
k_gat1(const int* __restrict__ offs, const int4* __restrict__ edg,
       const int* __restrict__ mask,
       const float* __restrict__ hL, const float* __restrict__ hG,
       const float* __restrict__ asL, const float* __restrict__ adL,
       const float* __restrict__ asG, const float* __restrict__ adG,
       const float* __restrict__ ae2, const float* __restrict__ eacc,
       float invE, const float* __restrict__ bL,
       const float* __restrict__ bG, float* __restrict__ C, int N) {
  int idx = blockIdx.x * blockDim.x + threadIdx.x;
  int n = idx >> 6, lane = idx & 63;
  if (n >= N) return;
  int m = mask[n];
  float v = gat_row(n, lane, m, offs, edg, hL, hG,
                    asL, adL, asG, adG, ae2, eacc, invE);
  C[(size_t)n * 64 + lane] = v + (m ? bG[lane] : bL[lane]);
}

// ---- BN stats: per-column sum & sumsq over C ----
__global__ void __launch_bounds__(256)
k_bnstat(const float* __restrict__ C, float* sums, float* sq, int N) {
  __shared__ float ls[256], lq[256];
  int col = threadIdx.x & 63, rg = threadIdx.x >> 6;
  float s = 0.f, q = 0.f;
  for (int r = blockIdx.x * 4 + rg; r < N; r += gridDim.x * 4) {
    float v = C[(size_t)r * 64 + col];
    s += v; q += v * v;
  }
  ls[threadIdx.x] = s; lq[threadIdx.x] = q;
  __syncthreads();
  if (rg == 0) {
    s = ls[col] + ls[col + 64] + ls[col + 128] + ls[col + 192];
    q = lq[col] + lq[col + 64] + lq[col + 128] + lq[col + 192];
    atomicAdd(&sums[col], s);
    atomicAdd(&sq[col], q);
  }
}

// ---- layer2 node features: BN+leaky inline, h2 = c@W, alphas = c.(W@a) ----
__global__ void __launch_bounds__(256)
k_node2(const float* __restrict__ C,
        const float* __restrict__ sums, const float* __restrict__ sq,
        const float* __restrict__ g, const float* __restrict__ beta,
        const float* __restrict__ WL, const float* __restrict__ WG,
        const float* __restrict__ was2,
        float* __restrict__ hL, float* __restrict__ hG,
        float* asL, float* adL, float* asG, float* adG, int N) {
  int idx = blockIdx.x * blockDim.x + threadIdx.x;
  int n = idx >> 6, lane = idx & 63;
  if (n >= N) return;
  float invN = 1.0f / (float)N;
  float mu = sums[lane] * invN;                  // col == lane
  float var = sq[lane] * invN - mu * mu;
  float v = C[(size_t)n * 64 + lane];
  v = (v - mu) * rsqrtf(var + BN_EPS) * g[lane] + beta[lane];
  float c = v >= 0.f ? v : NEG_ACT * v;
  float d0 = wred64(c * was2[lane]);         // c . (WL2@as2)
  float d1 = wred64(c * was2[64 + lane]);    // c . (WL2@ad2)
  float d2 = wred64(c * was2[128 + lane]);   // c . (WG2@as2)
  float d3 = wred64(c * was2[192 + lane]);   // c . (WG2@ad2)
  if (lane == 0) { asL[n] = d0; adL[n] = d1; asG[n] = d2; adG[n] = d3; }
  float accL = 0.f, accG = 0.f;
  #pragma unroll
  for (int k = 0; k < 64; k++) {
    float cb = __shfl(c, k);
    accL += cb * WL[k * 64 + lane];
    accG += cb * WG[k * 64 + lane];
  }
  hL[(size_t)n * 64 + lane] = accL;
  hG[(size_t)n * 64 + lane] = accG;
}

// ---- layer 2 GAT + bias + leaky + MLP(64->32->1) + mask, writes d_out ----
__global__ void __launch_bounds__(256)
k_gat2_mlp(const int* __restrict__ offs, const int4* __restrict__ edg,
           const int* __restrict__ mask,
           const float* __restrict__ hL, const float* __restrict__ hG,
           const float* __restrict__ asL, const float* __restrict__ adL,
           const float* __restrict__ asG, const float* __restrict__ adG,
           const float* __restrict__ ae2, const float* __restrict__ eacc,
           float invE, const float* __restrict__ bL,
           const float* __restrict__ bG,
           const float* __restrict__ f1W, const float* __restrict__ f1b,
           const float* __restrict__ f2W, const float* __restrict__ f2b,
           float* __restrict__ out, int N) {
  int idx = blockIdx.x * blockDim.x + threadIdx.x;
  int n = idx >> 6, lane = idx & 63;
  if (n >= N) return;
  int m = mask[n];
  float c = gat_row(n, lane, m, offs, edg, hL, hG,
                    asL, adL, asG, adG, ae2, eacc, invE)
          + (m ? bG[lane] : bL[lane]);
  c = c >= 0.f ? c : NEG_ACT * c;               // post-layer-2 activation
  float acc = 0.f;
  #pragma unroll
  for (int k = 0; k < 64; k++) {
    float cb = __shfl(c, k);
    if (lane < 32) acc += cb * f1W[k * 32 + lane];
  }
  float p = 0.f;
  if (lane < 32) {
    float t = acc + f1b[lane];
    t = t >= 0.f ? t : NEG_ACT * t;
    p = t * f2W[lane];
  }
  p = wred64(p);
  if (lane == 0) out[n] = (p + f2b[0]) * (float)m;
}

extern "C" void kernel_launch(void* const* d_in, const int* in_sizes, int n_in,
                              void* d_out, int out_size, void* d_ws, size_t ws_size,
                              hipStream_t stream) {
  const float* x     = (const float*)d_in[0];
  const float* eattr = (const float*)d_in[1];
  const int*   ei    = (const int*)d_in[2];
  const int*   mask  = (const int*)d_in[3];
  const float* gcn_W  = (const float*)d_in[4];
  const float* gcn_We = (const float*)d_in[5];
  const float* gcn_as = (const float*)d_in[6];
  const float* gcn_ad = (const float*)d_in[7];
  const float* gcn_ae = (const float*)d_in[8];
  const float* gcn_b  = (const float*)d_in[9];
  const float* lit_W  = (const float*)d_in[10];
  const float* lit_We = (const float*)d_in[11];
  const float* lit_as = (const float*)d_in[12];
  const float* lit_ad = (const float*)d_in[13];
  const float* lit_ae = (const float*)d_in[14];
  const float* lit_b  = (const float*)d_in[15];
  const float* gcn2_W  = (const float*)d_in[16];
  const float* gcn2_We = (const float*)d_in[17];
  const float* gcn2_as = (const float*)d_in[18];
  const float* gcn2_ad = (const float*)d_in[19];
  const float* gcn2_ae = (const float*)d_in[20];
  const float* gcn2_b  = (const float*)d_in[21];
  const float* lit2_W  = (const float*)d_in[22];
  const float* lit2_We = (const float*)d_in[23];
  const float* lit2_as = (const float*)d_in[24];
  const float* lit2_ad = (const float*)d_in[25];
  const float* lit2_ae = (const float*)d_in[26];
  const float* lit2_b  = (const float*)d_in[27];
  const float* ln_g    = (const float*)d_in[28];
  const float* ln_beta = (const float*)d_in[29];
  const float* f1W = (const float*)d_in[30];
  const float* f1b = (const float*)d_in[31];
  const float* f2W = (const float*)d_in[32];
  const float* f2b = (const float*)d_in[33];

  const int N = in_sizes[3];
  const int E = in_sizes[1] / 2;
  const size_t N64 = (size_t)N * 64;

  // ---- workspace layout (4-byte units); edg first for 16B alignment ----
  int4*  edg   = (int4*)d_ws;              // E packed (src, as+et, et2, mask)
  float* C     = (float*)(edg + E);        // N*64
  float* A     = C + N64;                  // N*64 (h lit)
  float* B     = A + N64;                  // N*64 (h gcn)
  int*   cnt   = (int*)(B + N64);          // N   [memset region start]
  float* sums  = (float*)(cnt + N);        // 64
  float* sq    = sums + 64;                // 64
  float* eacc  = sq + 64;                  // 2   [memset region end]
  float* ae2   = eacc + 2;                 // 8
  float* l1c   = ae2 + 8;                  // 8
  float* was2  = l1c + 8;                  // 256
  int*   offs  = (int*)(was2 + 256);       // N+1
  int*   cur   = offs + N + 1;             // N
  int*   bsum  = cur + N;                  // <=1024
  float* asL   = (float*)(bsum + 1024);    // N
  float* adL   = asL + N;                  // N
  float* asG   = adL + N;                  // N
  float* adG   = asG + N;                  // N

  const float invE = 1.0f / (float)E;
  const int TB = 256;
  const int nodeBlocks = (int)((N64 + TB - 1) / TB);   // wave-per-node kernels
  const int eBlocks = (E + TB - 1) / TB;               // thread-per-edge kernels
  const int nb = (N + 1023) / 1024;                    // scan chunks

  // zero cnt, sums, sq, eacc (contiguous)
  hipMemsetAsync(cnt, 0, ((size_t)N + 130) * sizeof(float), stream);

  // ---- constants + CSR build (graph shared by both layers) ----
  k_prep<<<1, 64, 0, stream>>>(lit_W, lit_We, lit_as, lit_ad, lit_ae,
                               gcn_W, gcn_We, gcn_as, gcn_ad, gcn_ae,
                               lit2_W, lit2_We, lit2_as, lit2_ad, lit2_ae,
                               gcn2_W, gcn2_We, gcn2_as, gcn2_ad, gcn2_ae,
                               ae2, l1c, was2);
  k_eamean<<<1024, TB, 0, stream>>>(eattr, eacc, E);
  k_hist<<<eBlocks, TB, 0, stream>>>(ei, cnt, E);
  k_scanA<<<nb, TB, 0, stream>>>(cnt, bsum, N);
  k_scanB<<<1, 1024, 0, stream>>>(bsum, offs, nb, E, N);
  k_scanC<<<nb, TB, 0, stream>>>(cnt, bsum, offs, cur, N);
  // node1 BEFORE fill: layer-1 alpha_src gets folded into edge records
  k_node1<<<nodeBlocks, TB, 0, stream>>>(x, lit_W, gcn_W, l1c,
                                         A, B, asL, adL, asG, adG, N);
  k_fill<<<eBlocks, TB, 0, stream>>>(ei, eattr, mask, ae2, asL, asG,
                                     cur, edg, E);
  // ---- layer 1 ----
  k_gat1<<<nodeBlocks, TB, 0, stream>>>(offs, edg, mask, A, B,
                                        asL, adL, asG, adG, ae2, eacc, invE,
                                        lit_b, gcn_b, C, N);
  // ---- BN stats (apply fused into k_node2) ----
  k_bnstat<<<384, TB, 0, stream>>>(C, sums, sq, N);
  // ---- layer 2 ----
  k_node2<<<nodeBlocks, TB, 0, stream>>>(C, sums, sq, ln_g, ln_beta,
                                         lit2_W, gcn2_W, was2,
                                         A, B, asL, adL, asG, adG, N);
  // refill: fold layer-2 alpha_src into records (2-stream gather for layer 2)
  k_refill<<<eBlocks, TB, 0, stream>>>(asL, asG, edg, E);
  k_gat2_mlp<<<nodeBlocks, TB, 0, stream>>>(offs, edg, mask, A, B,
                                            asL, adL, asG, adG, ae2 + 4, eacc, invE,
                                            lit2_b, gcn2_b, f1W, f1b, f2W, f2b,
                                            (float*)d_out, N);
}

// Round 11
// 865.791 us; speedup vs baseline: 1.0183x; 1.0183x over previous
//
#include <hip/hip_runtime.h>

#define NEG_GAT 0.2f
#define NEG_ACT 0.01f
#define BN_EPS 1e-5f

__device__ __forceinline__ float wred64(float v) {
  #pragma unroll
  for (int o = 32; o; o >>= 1) v += __shfl_down(v, o);
  return v;
}
__device__ __forceinline__ int wredi64(int v) {
  #pragma unroll
  for (int o = 32; o; o >>= 1) v += __shfl_down(v, o);
  return v;
}
// inclusive wave scan (64 lanes)
__device__ __forceinline__ int wscani(int x, int lane) {
  #pragma unroll
  for (int off = 1; off < 64; off <<= 1) {
    int t = __shfl_up(x, off);
    if (lane >= off) x += t;
  }
  return x;
}

// ---- precompute all small constants:
//  ae2[8]   : We@ae per set                (2 scalars x {L1,G1,L2,G2})
//  l1c[8]   : W1@as, W1@ad per layer-1 set (2+2 scalars x {L,G})
//  was2[256]: W2@as2, W2@ad2 per layer-2 set (64+64 x {L,G})
__global__ void k_prep(const float* WL1, const float* WeL1, const float* asL1,
                       const float* adL1, const float* aeL1,
                       const float* WG1, const float* WeG1, const float* asG1,
                       const float* adG1, const float* aeG1,
                       const float* WL2, const float* WeL2, const float* asL2,
                       const float* adL2, const float* aeL2,
                       const float* WG2, const float* WeG2, const float* asG2,
                       const float* adG2, const float* aeG2,
                       float* ae2, float* l1c, float* was2) {
  int lane = threadIdx.x;  // 64 threads
  const float* We[4] = {WeL1, WeG1, WeL2, WeG2};
  const float* ae[4] = {aeL1, aeG1, aeL2, aeG2};
  for (int s = 0; s < 4; s++) {
    float v0 = wred64(We[s][lane] * ae[s][lane]);
    float v1 = wred64(We[s][64 + lane] * ae[s][lane]);
    if (lane == 0) { ae2[2 * s] = v0; ae2[2 * s + 1] = v1; }
  }
  const float* W1[2] = {WL1, WG1};
  const float* a1s[2] = {asL1, asG1};
  const float* a1d[2] = {adL1, adG1};
  for (int t = 0; t < 2; t++) {
    float ws0 = wred64(W1[t][lane] * a1s[t][lane]);
    float ws1 = wred64(W1[t][64 + lane] * a1s[t][lane]);
    float wd0 = wred64(W1[t][lane] * a1d[t][lane]);
    float wd1 = wred64(W1[t][64 + lane] * a1d[t][lane]);
    if (lane == 0) {
      l1c[4 * t + 0] = ws0; l1c[4 * t + 1] = ws1;
      l1c[4 * t + 2] = wd0; l1c[4 * t + 3] = wd1;
    }
  }
  const float* W2[2] = {WL2, WG2};
  const float* a2s[2] = {asL2, asG2};
  const float* a2d[2] = {adL2, adG2};
  for (int t = 0; t < 2; t++) {
    float ss = 0.f, sd = 0.f;
    for (int j = 0; j < 64; j++) {
      float w = W2[t][lane * 64 + j];
      ss += w * a2s[t][j];
      sd += w * a2d[t][j];
    }
    was2[(2 * t) * 64 + lane] = ss;       // @as
    was2[(2 * t + 1) * 64 + lane] = sd;   // @ad
  }
}

// ---- edge_attr column sums (for mean fill of self-loop attrs) ----
__global__ void __launch_bounds__(256)
k_eamean(const float* __restrict__ eattr, float* acc, int E) {
  int i = blockIdx.x * blockDim.x + threadIdx.x;
  float s0 = 0.f, s1 = 0.f;
  for (int e = i; e < E; e += gridDim.x * blockDim.x) {
    float2 v = ((const float2*)eattr)[e];
    s0 += v.x; s1 += v.y;
  }
  s0 = wred64(s0);
  s1 = wred64(s1);
  if ((threadIdx.x & 63) == 0) {
    atomicAdd(&acc[0], s0);
    atomicAdd(&acc[1], s1);
  }
}

// ---- CSR 1: in-degree histogram ----
__global__ void __launch_bounds__(256)
k_hist(const int* __restrict__ ei, int* __restrict__ cnt, int E) {
  int e = blockIdx.x * blockDim.x + threadIdx.x;
  if (e < E) atomicAdd(&cnt[ei[E + e]], 1);
}

// ---- CSR 2a: per-chunk (1024-elem) sums ----
__global__ void __launch_bounds__(256)
k_scanA(const int* __restrict__ cnt, int* __restrict__ bsum, int N) {
  __shared__ int wsum[4];
  int tid = threadIdx.x, lane = tid & 63, wid = tid >> 6;
  int base = blockIdx.x * 1024 + tid * 4;
  int t = 0;
  if (base + 3 < N) {
    int4 q = *(const int4*)(cnt + base);
    t = q.x + q.y + q.z + q.w;
  } else {
    if (base < N) t += cnt[base];
    if (base + 1 < N) t += cnt[base + 1];
    if (base + 2 < N) t += cnt[base + 2];
    if (base + 3 < N) t += cnt[base + 3];
  }
  t = wredi64(t);
  if (lane == 0) wsum[wid] = t;
  __syncthreads();
  if (tid == 0) bsum[blockIdx.x] = wsum[0] + wsum[1] + wsum[2] + wsum[3];
}

// ---- CSR 2b: exclusive scan of chunk sums (nb <= 1024); also offs[N]=E ----
__global__ void __launch_bounds__(1024)
k_scanB(int* __restrict__ bsum, int* __restrict__ offs, int nb, int E, int N) {
  __shared__ int wsum[16];
  int tid = threadIdx.x, lane = tid & 63, wid = tid >> 6;
  int v = (tid < nb) ? bsum[tid] : 0;
  int x = wscani(v, lane);
  if (lane == 63) wsum[wid] = x;
  __syncthreads();
  if (wid == 0) {
    int w = (lane < 16) ? wsum[lane] : 0;
    w = wscani(w, lane);
    if (lane < 16) wsum[lane] = w;
  }
  __syncthreads();
  int incl = x + (wid ? wsum[wid - 1] : 0);
  if (tid < nb) bsum[tid] = incl - v;   // exclusive
  if (tid == 0) offs[N] = E;
}

// ---- CSR 2c: chunk-local exclusive scan + chunk base -> offs, cur ----
__global__ void __launch_bounds__(256)
k_scanC(const int* __restrict__ cnt, const int* __restrict__ bsum,
        int* __restrict__ offs, int* __restrict__ cur, int N) {
  __shared__ int wsum[4];
  int tid = threadIdx.x, lane = tid & 63, wid = tid >> 6;
  int base = blockIdx.x * 1024 + tid * 4;
  int v0 = 0, v1 = 0, v2 = 0, v3 = 0;
  if (base + 3 < N) {
    int4 q = *(const int4*)(cnt + base);
    v0 = q.x; v1 = q.y; v2 = q.z; v3 = q.w;
  } else {
    if (base < N) v0 = cnt[base];
    if (base + 1 < N) v1 = cnt[base + 1];
    if (base + 2 < N) v2 = cnt[base + 2];
    if (base + 3 < N) v3 = cnt[base + 3];
  }
  int t = v0 + v1 + v2 + v3;
  int incl = wscani(t, lane);
  int exclT = incl - t;
  if (lane == 63) wsum[wid] = incl;
  __syncthreads();
  int wb = 0;
  if (wid > 0) wb += wsum[0];
  if (wid > 1) wb += wsum[1];
  if (wid > 2) wb += wsum[2];
  int eb = bsum[blockIdx.x] + wb + exclT;
  if (base < N)     { offs[base] = eb;           cur[base] = eb; }
  if (base + 1 < N) { int u = eb + v0;           offs[base + 1] = u; cur[base + 1] = u; }
  if (base + 2 < N) { int u = eb + v0 + v1;      offs[base + 2] = u; cur[base + 2] = u; }
  if (base + 3 < N) { int u = eb + v0 + v1 + v2; offs[base + 3] = u; cur[base + 3] = u; }
}

// ---- layer1 node features: h = x@W; alphas via precomputed W@a (2 FMAs) ----
// (runs BEFORE k_fill so layer-1 alpha_src can be folded into edge records)
__global__ void __launch_bounds__(256)
k_node1(const float* __restrict__ x,
        const float* __restrict__ WL, const float* __restrict__ WG,
        const float* __restrict__ l1c,
        float* __restrict__ hL, float* __restrict__ hG,
        float* asL, float* adL, float* asG, float* adG, int N) {
  int idx = blockIdx.x * blockDim.x + threadIdx.x;
  int n = idx >> 6, lane = idx & 63;
  if (n >= N) return;
  float2 xv = ((const float2*)x)[n];
  hL[(size_t)n * 64 + lane] = xv.x * WL[lane] + xv.y * WL[64 + lane];
  hG[(size_t)n * 64 + lane] = xv.x * WG[lane] + xv.y * WG[64 + lane];
  if (lane == 0) {
    asL[n] = xv.x * l1c[0] + xv.y * l1c[1];
    adL[n] = xv.x * l1c[2] + xv.y * l1c[3];
    asG[n] = xv.x * l1c[4] + xv.y * l1c[5];
    adG[n] = xv.x * l1c[6] + xv.y * l1c[7];
  }
}

// ---- CSR 3: fill packed (src, as1[src]+et1, et2, mask) records, dst-sorted ----
__global__ void __launch_bounds__(256)
k_fill(const int* __restrict__ ei, const float* __restrict__ eattr,
       const int* __restrict__ mask, const float* __restrict__ ae2,
       const float* __restrict__ asL1, const float* __restrict__ asG1,
       int* __restrict__ cur, int4* __restrict__ edg, int E) {
  int e = blockIdx.x * blockDim.x + threadIdx.x;
  if (e >= E) return;
  int s = ei[e], d = ei[E + e];
  int m = mask[d];
  float2 ea = ((const float2*)eattr)[e];
  float as1 = m ? asG1[s] : asL1[s];
  float t1 = as1 + ea.x * (m ? ae2[2] : ae2[0]) + ea.y * (m ? ae2[3] : ae2[1]);
  float t2 =       ea.x * (m ? ae2[6] : ae2[4]) + ea.y * (m ? ae2[7] : ae2[5]);
  int j = atomicAdd(&cur[d], 1);
  edg[j] = make_int4(s, __float_as_int(t1), __float_as_int(t2), m);
}

// ---- refill pass (after k_node2): .y <- as2[src] + et2, so layer 2's gather
//      loop matches layer 1's form. Thread-per-edge, streaming. ----
__global__ void __launch_bounds__(256)
k_refill(const float* __restrict__ asL2, const float* __restrict__ asG2,
         int4* __restrict__ edg, int E) {
  int j = blockIdx.x * blockDim.x + threadIdx.x;
  if (j >= E) return;
  int4 v = edg[j];
  float as2 = (v.w ? asG2 : asL2)[v.x];
  edg[j].y = __float_as_int(as2 + __int_as_float(v.z));
}

// ---- GAT row aggregation, 4 edges per wave-instruction.
//      Wave = 4 groups x 16 lanes; group g handles edge j+g, lane reads a
//      float4 (16B) of the 256B h-row. 8 edges per loop iter (2 quads in
//      flight). Tail edges: record index clamped to end-1 (L1-hot duplicate)
//      and ex masked to 0. Cross-group combine: shfl_xor butterfly (16,32).
//      Max-subtraction dropped: |logit| <= ~6 by construction; exp(m) cancels
//      exactly in coef = ex/denom. logit = rec.y + ad (alpha_src prefolded).
//      Result: all 64 lanes hold dims [(lane&15)*4 .. +3] of the GAT row. ----
__device__ __forceinline__ float4 gat_row4(
    int n, int lane, int m,
    const int* __restrict__ offs, const int4* __restrict__ edg,
    const float* __restrict__ hL, const float* __restrict__ hG,
    const float* __restrict__ asL, const float* __restrict__ adL,
    const float* __restrict__ asG, const float* __restrict__ adG,
    const float* __restrict__ ae2, const float* __restrict__ eacc, float invE) {
  const float* as_p = m ? asG : asL;
  const float4* h4  = (const float4*)(m ? hG : hL);
  float ad = (m ? adG : adL)[n];
  float k0 = m ? ae2[2] : ae2[0];
  float k1 = m ? ae2[3] : ae2[1];
  int sub = lane & 15, grp = lane >> 4;
  // self loop (ea = column means); counted in group 0 only
  float lg = as_p[n] + ad + (eacc[0] * invE) * k0 + (eacc[1] * invE) * k1;
  lg = lg >= 0.f ? lg : NEG_GAT * lg;
  float exs = __expf(lg);
  float4 hs = h4[(size_t)n * 16 + sub];
  float w = (grp == 0) ? exs : 0.f;
  float ax = w * hs.x, ay = w * hs.y, az = w * hs.z, aw = w * hs.w;
  float denom = w;
  int j = offs[n], end = offs[n + 1];
  for (; j < end; j += 8) {
    int i0 = j + grp, i1 = j + 4 + grp;
    int c0 = i0 < end ? i0 : end - 1;
    int c1 = i1 < end ? i1 : end - 1;
    int4 r0 = edg[(size_t)c0];
    int4 r1 = edg[(size_t)c1];
    float4 h0 = h4[(size_t)r0.x * 16 + sub];
    float4 h1 = h4[(size_t)r1.x * 16 + sub];
    float l0 = __int_as_float(r0.y) + ad;
    float l1 = __int_as_float(r1.y) + ad;
    l0 = l0 >= 0.f ? l0 : NEG_GAT * l0;
    l1 = l1 >= 0.f ? l1 : NEG_GAT * l1;
    float e0 = (i0 < end) ? __expf(l0) : 0.f;
    float e1 = (i1 < end) ? __expf(l1) : 0.f;
    denom += e0 + e1;
    ax = fmaf(e0, h0.x, ax); ay = fmaf(e0, h0.y, ay);
    az = fmaf(e0, h0.z, az); aw = fmaf(e0, h0.w, aw);
    ax = fmaf(e1, h1.x, ax); ay = fmaf(e1, h1.y, ay);
    az = fmaf(e1, h1.z, az); aw = fmaf(e1, h1.w, aw);
  }
  // combine the 4 group-partials (lane bits 4,5)
  #pragma unroll
  for (int off = 16; off < 64; off <<= 1) {
    ax += __shfl_xor(ax, off); ay += __shfl_xor(ay, off);
    az += __shfl_xor(az, off); aw += __shfl_xor(aw, off);
    denom += __shfl_xor(denom, off);
  }
  float inv = 1.f / denom;
  return make_float4(ax * inv, ay * inv, az * inv, aw * inv);
}

// ---- layer 1: GAT -> C = out + bias (float4 row write from lanes 0..15) ----
__global__ void __launch_bounds__(256)
k_gat1(const int* __restrict__ offs, const int4* __restrict__ edg,
       const int* __restrict__ mask,
       const float* __restrict__ hL, const float* __restrict__ hG,
       const float* __restrict__ asL, const float* __restrict__ adL,
       const float* __restrict__ asG, const float* __restrict__ adG,
       const float* __restrict__ ae2, const float* __restrict__ eacc,
       float invE, const float* __restrict__ bL,
       const float* __restrict__ bG, float* __restrict__ C, int N) {
  int idx = blockIdx.x * blockDim.x + threadIdx.x;
  int n = idx >> 6, lane = idx & 63;
  if (n >= N) return;
  int m = mask[n];
  float4 o = gat_row4(n, lane, m, offs, edg, hL, hG,
                      asL, adL, asG, adG, ae2, eacc, invE);
  if (lane < 16) {
    float4 b4 = ((const float4*)(m ? bG : bL))[lane];
    o.x += b4.x; o.y += b4.y; o.z += b4.z; o.w += b4.w;
    ((float4*)C)[(size_t)n * 16 + lane] = o;
  }
}

// ---- BN stats: per-column sum & sumsq over C ----
__global__ void __launch_bounds__(256)
k_bnstat(const float* __restrict__ C, float* sums, float* sq, int N) {
  __shared__ float ls[256], lq[256];
  int col = threadIdx.x & 63, rg = threadIdx.x >> 6;
  float s = 0.f, q = 0.f;
  for (int r = blockIdx.x * 4 + rg; r < N; r += gridDim.x * 4) {
    float v = C[(size_t)r * 64 + col];
    s += v; q += v * v;
  }
  ls[threadIdx.x] = s; lq[threadIdx.x] = q;
  __syncthreads();
  if (rg == 0) {
    s = ls[col] + ls[col + 64] + ls[col + 128] + ls[col + 192];
    q = lq[col] + lq[col + 64] + lq[col + 128] + lq[col + 192];
    atomicAdd(&sums[col], s);
    atomicAdd(&sq[col], q);
  }
}

// ---- layer2 node features: BN+leaky inline, h2 = c@W, alphas = c.(W@a) ----
__global__ void __launch_bounds__(256)
k_node2(const float* __restrict__ C,
        const float* __restrict__ sums, const float* __restrict__ sq,
        const float* __restrict__ g, const float* __restrict__ beta,
        const float* __restrict__ WL, const float* __restrict__ WG,
        const float* __restrict__ was2,
        float* __restrict__ hL, float* __restrict__ hG,
        float* asL, float* adL, float* asG, float* adG, int N) {
  int idx = blockIdx.x * blockDim.x + threadIdx.x;
  int n = idx >> 6, lane = idx & 63;
  if (n >= N) return;
  float invN = 1.0f / (float)N;
  float mu = sums[lane] * invN;                  // col == lane
  float var = sq[lane] * invN - mu * mu;
  float v = C[(size_t)n * 64 + lane];
  v = (v - mu) * rsqrtf(var + BN_EPS) * g[lane] + beta[lane];
  float c = v >= 0.f ? v : NEG_ACT * v;
  float d0 = wred64(c * was2[lane]);         // c . (WL2@as2)
  float d1 = wred64(c * was2[64 + lane]);    // c . (WL2@ad2)
  float d2 = wred64(c * was2[128 + lane]);   // c . (WG2@as2)
  float d3 = wred64(c * was2[192 + lane]);   // c . (WG2@ad2)
  if (lane == 0) { asL[n] = d0; adL[n] = d1; asG[n] = d2; adG[n] = d3; }
  float accL = 0.f, accG = 0.f;
  #pragma unroll
  for (int k = 0; k < 64; k++) {
    float cb = __shfl(c, k);
    accL += cb * WL[k * 64 + lane];
    accG += cb * WG[k * 64 + lane];
  }
  hL[(size_t)n * 64 + lane] = accL;
  hG[(size_t)n * 64 + lane] = accG;
}

// ---- layer 2 GAT + bias + leaky + MLP(64->32->1) + mask, writes d_out ----
__global__ void __launch_bounds__(256)
k_gat2_mlp(const int* __restrict__ offs, const int4* __restrict__ edg,
           const int* __restrict__ mask,
           const float* __restrict__ hL, const float* __restrict__ hG,
           const float* __restrict__ asL, const float* __restrict__ adL,
           const float* __restrict__ asG, const float* __restrict__ adG,
           const float* __restrict__ ae2, const float* __restrict__ eacc,
           float invE, const float* __restrict__ bL,
           const float* __restrict__ bG,
           const float* __restrict__ f1W, const float* __restrict__ f1b,
           const float* __restrict__ f2W, const float* __restrict__ f2b,
           float* __restrict__ out, int N) {
  int idx = blockIdx.x * blockDim.x + threadIdx.x;
  int n = idx >> 6, lane = idx & 63;
  if (n >= N) return;
  int m = mask[n];
  float4 o = gat_row4(n, lane, m, offs, edg, hL, hG,
                      asL, adL, asG, adG, ae2, eacc, invE);
  float4 b4 = ((const float4*)(m ? bG : bL))[lane & 15];
  float cv[4];
  cv[0] = o.x + b4.x; cv[1] = o.y + b4.y;
  cv[2] = o.z + b4.z; cv[3] = o.w + b4.w;
  #pragma unroll
  for (int q = 0; q < 4; q++)
    cv[q] = cv[q] >= 0.f ? cv[q] : NEG_ACT * cv[q];   // post-layer-2 activation
  // c[k] lives in component k&3 of lane (k>>2); all lanes hold the full row.
  float acc = 0.f;
  #pragma unroll
  for (int k = 0; k < 64; k++) {
    float cb = __shfl(cv[k & 3], k >> 2);
    if (lane < 32) acc = fmaf(cb, f1W[k * 32 + lane], acc);
  }
  float p = 0.f;
  if (lane < 32) {
    float t = acc + f1b[lane];
    t = t >= 0.f ? t : NEG_ACT * t;
    p = t * f2W[lane];
  }
  p = wred64(p);
  if (lane == 0) out[n] = (p + f2b[0]) * (float)m;
}

extern "C" void kernel_launch(void* const* d_in, const int* in_sizes, int n_in,
                              void* d_out, int out_size, void* d_ws, size_t ws_size,
                              hipStream_t stream) {
  const float* x     = (const float*)d_in[0];
  const float* eattr = (const float*)d_in[1];
  const int*   ei    = (const int*)d_in[2];
  const int*   mask  = (const int*)d_in[3];
  const float* gcn_W  = (const float*)d_in[4];
  const float* gcn_We = (const float*)d_in[5];
  const float* gcn_as = (const float*)d_in[6];
  const float* gcn_ad = (const float*)d_in[7];
  const float* gcn_ae = (const float*)d_in[8];
  const float* gcn_b  = (const float*)d_in[9];
  const float* lit_W  = (const float*)d_in[10];
  const float* lit_We = (const float*)d_in[11];
  const float* lit_as = (const float*)d_in[12];
  const float* lit_ad = (const float*)d_in[13];
  const float* lit_ae = (const float*)d_in[14];
  const float* lit_b  = (const float*)d_in[15];
  const float* gcn2_W  = (const float*)d_in[16];
  const float* gcn2_We = (const float*)d_in[17];
  const float* gcn2_as = (const float*)d_in[18];
  const float* gcn2_ad = (const float*)d_in[19];
  const float* gcn2_ae = (const float*)d_in[20];
  const float* gcn2_b  = (const float*)d_in[21];
  const float* lit2_W  = (const float*)d_in[22];
  const float* lit2_We = (const float*)d_in[23];
  const float* lit2_as = (const float*)d_in[24];
  const float* lit2_ad = (const float*)d_in[25];
  const float* lit2_ae = (const float*)d_in[26];
  const float* lit2_b  = (const float*)d_in[27];
  const float* ln_g    = (const float*)d_in[28];
  const float* ln_beta = (const float*)d_in[29];
  const float* f1W = (const float*)d_in[30];
  const float* f1b = (const float*)d_in[31];
  const float* f2W = (const float*)d_in[32];
  const float* f2b = (const float*)d_in[33];

  const int N = in_sizes[3];
  const int E = in_sizes[1] / 2;
  const size_t N64 = (size_t)N * 64;

  // ---- workspace layout (4-byte units); edg first for 16B alignment ----
  int4*  edg   = (int4*)d_ws;              // E packed (src, as+et, et2, mask)
  float* C     = (float*)(edg + E);        // N*64
  float* A     = C + N64;                  // N*64 (h lit)
  float* B     = A + N64;                  // N*64 (h gcn)
  int*   cnt   = (int*)(B + N64);          // N   [memset region start]
  float* sums  = (float*)(cnt + N);        // 64
  float* sq    = sums + 64;                // 64
  float* eacc  = sq + 64;                  // 2   [memset region end]
  float* ae2   = eacc + 2;                 // 8
  float* l1c   = ae2 + 8;                  // 8
  float* was2  = l1c + 8;                  // 256
  int*   offs  = (int*)(was2 + 256);       // N+1
  int*   cur   = offs + N + 1;             // N
  int*   bsum  = cur + N;                  // <=1024
  float* asL   = (float*)(bsum + 1024);    // N
  float* adL   = asL + N;                  // N
  float* asG   = adL + N;                  // N
  float* adG   = asG + N;                  // N

  const float invE = 1.0f / (float)E;
  const int TB = 256;
  const int nodeBlocks = (int)((N64 + TB - 1) / TB);   // wave-per-node kernels
  const int eBlocks = (E + TB - 1) / TB;               // thread-per-edge kernels
  const int nb = (N + 1023) / 1024;                    // scan chunks

  // zero cnt, sums, sq, eacc (contiguous)
  hipMemsetAsync(cnt, 0, ((size_t)N + 130) * sizeof(float), stream);

  // ---- constants + CSR build (graph shared by both layers) ----
  k_prep<<<1, 64, 0, stream>>>(lit_W, lit_We, lit_as, lit_ad, lit_ae,
                               gcn_W, gcn_We, gcn_as, gcn_ad, gcn_ae,
                               lit2_W, lit2_We, lit2_as, lit2_ad, lit2_ae,
                               gcn2_W, gcn2_We, gcn2_as, gcn2_ad, gcn2_ae,
                               ae2, l1c, was2);
  k_eamean<<<1024, TB, 0, stream>>>(eattr, eacc, E);
  k_hist<<<eBlocks, TB, 0, stream>>>(ei, cnt, E);
  k_scanA<<<nb, TB, 0, stream>>>(cnt, bsum, N);
  k_scanB<<<1, 1024, 0, stream>>>(bsum, offs, nb, E, N);
  k_scanC<<<nb, TB, 0, stream>>>(cnt, bsum, offs, cur, N);
  // node1 BEFORE fill: layer-1 alpha_src gets folded into edge records
  k_node1<<<nodeBlocks, TB, 0, stream>>>(x, lit_W, gcn_W, l1c,
                                         A, B, asL, adL, asG, adG, N);
  k_fill<<<eBlocks, TB, 0, stream>>>(ei, eattr, mask, ae2, asL, asG,
                                     cur, edg, E);
  // ---- layer 1 ----
  k_gat1<<<nodeBlocks, TB, 0, stream>>>(offs, edg, mask, A, B,
                                        asL, adL, asG, adG, ae2, eacc, invE,
                                        lit_b, gcn_b, C, N);
  // ---- BN stats (apply fused into k_node2) ----
  k_bnstat<<<384, TB, 0, stream>>>(C, sums, sq, N);
  // ---- layer 2 ----
  k_node2<<<nodeBlocks, TB, 0, stream>>>(C, sums, sq, ln_g, ln_beta,
                                         lit2_W, gcn2_W, was2,
                                         A, B, asL, adL, asG, adG, N);
  // refill: fold layer-2 alpha_src into records (uniform gather loop form)
  k_refill<<<eBlocks, TB, 0, stream>>>(asL, asG, edg, E);
  k_gat2_mlp<<<nodeBlocks, TB, 0, stream>>>(offs, edg, mask, A, B,
                                            asL, adL, asG, adG, ae2 + 4, eacc, invE,
                                            lit2_b, gcn2_b, f1W, f1b, f2W, f2b,
                                            (float*)d_out, N);
}

// Round 14
// 741.256 us; speedup vs baseline: 1.1893x; 1.1680x over previous
//
#include <hip/hip_runtime.h>

#define NEG_GAT 0.2f
#define NEG_ACT 0.01f
#define BN_EPS 1e-5f

__device__ __forceinline__ float wred64(float v) {
  #pragma unroll
  for (int o = 32; o; o >>= 1) v += __shfl_down(v, o);
  return v;
}
__device__ __forceinline__ int wredi64(int v) {
  #pragma unroll
  for (int o = 32; o; o >>= 1) v += __shfl_down(v, o);
  return v;
}
// inclusive wave scan (64 lanes)
__device__ __forceinline__ int wscani(int x, int lane) {
  #pragma unroll
  for (int off = 1; off < 64; off <<= 1) {
    int t = __shfl_up(x, off);
    if (lane >= off) x += t;
  }
  return x;
}

// ---- precompute all small constants:
//  ae2[8]   : We@ae per set                (2 scalars x {L1,G1,L2,G2})
//  l1c[8]   : W1@as, W1@ad per layer-1 set (2+2 scalars x {L,G})
//  was2[256]: W2@as2, W2@ad2 per layer-2 set (64+64 x {L,G})
__global__ void k_prep(const float* WL1, const float* WeL1, const float* asL1,
                       const float* adL1, const float* aeL1,
                       const float* WG1, const float* WeG1, const float* asG1,
                       const float* adG1, const float* aeG1,
                       const float* WL2, const float* WeL2, const float* asL2,
                       const float* adL2, const float* aeL2,
                       const float* WG2, const float* WeG2, const float* asG2,
                       const float* adG2, const float* aeG2,
                       float* ae2, float* l1c, float* was2) {
  int lane = threadIdx.x;  // 64 threads
  const float* We[4] = {WeL1, WeG1, WeL2, WeG2};
  const float* ae[4] = {aeL1, aeG1, aeL2, aeG2};
  for (int s = 0; s < 4; s++) {
    float v0 = wred64(We[s][lane] * ae[s][lane]);
    float v1 = wred64(We[s][64 + lane] * ae[s][lane]);
    if (lane == 0) { ae2[2 * s] = v0; ae2[2 * s + 1] = v1; }
  }
  const float* W1[2] = {WL1, WG1};
  const float* a1s[2] = {asL1, asG1};
  const float* a1d[2] = {adL1, adG1};
  for (int t = 0; t < 2; t++) {
    float ws0 = wred64(W1[t][lane] * a1s[t][lane]);
    float ws1 = wred64(W1[t][64 + lane] * a1s[t][lane]);
    float wd0 = wred64(W1[t][lane] * a1d[t][lane]);
    float wd1 = wred64(W1[t][64 + lane] * a1d[t][lane]);
    if (lane == 0) {
      l1c[4 * t + 0] = ws0; l1c[4 * t + 1] = ws1;
      l1c[4 * t + 2] = wd0; l1c[4 * t + 3] = wd1;
    }
  }
  const float* W2[2] = {WL2, WG2};
  const float* a2s[2] = {asL2, asG2};
  const float* a2d[2] = {adL2, adG2};
  for (int t = 0; t < 2; t++) {
    float ss = 0.f, sd = 0.f;
    for (int j = 0; j < 64; j++) {
      float w = W2[t][lane * 64 + j];
      ss += w * a2s[t][j];
      sd += w * a2d[t][j];
    }
    was2[(2 * t) * 64 + lane] = ss;       // @as
    was2[(2 * t + 1) * 64 + lane] = sd;   // @ad
  }
}

// ---- edge_attr column sums (for mean fill of self-loop attrs) ----
__global__ void __launch_bounds__(256)
k_eamean(const float* __restrict__ eattr, float* acc, int E) {
  int i = blockIdx.x * blockDim.x + threadIdx.x;
  float s0 = 0.f, s1 = 0.f;
  for (int e = i; e < E; e += gridDim.x * blockDim.x) {
    float2 v = ((const float2*)eattr)[e];
    s0 += v.x; s1 += v.y;
  }
  s0 = wred64(s0);
  s1 = wred64(s1);
  if ((threadIdx.x & 63) == 0) {
    atomicAdd(&acc[0], s0);
    atomicAdd(&acc[1], s1);
  }
}

// ---- CSR 1: in-degree histogram ----
__global__ void __launch_bounds__(256)
k_hist(const int* __restrict__ ei, int* __restrict__ cnt, int E) {
  int e = blockIdx.x * blockDim.x + threadIdx.x;
  if (e < E) atomicAdd(&cnt[ei[E + e]], 1);
}

// ---- CSR 2a: per-chunk (1024-elem) sums ----
__global__ void __launch_bounds__(256)
k_scanA(const int* __restrict__ cnt, int* __restrict__ bsum, int N) {
  __shared__ int wsum[4];
  int tid = threadIdx.x, lane = tid & 63, wid = tid >> 6;
  int base = blockIdx.x * 1024 + tid * 4;
  int t = 0;
  if (base + 3 < N) {
    int4 q = *(const int4*)(cnt + base);
    t = q.x + q.y + q.z + q.w;
  } else {
    if (base < N) t += cnt[base];
    if (base + 1 < N) t += cnt[base + 1];
    if (base + 2 < N) t += cnt[base + 2];
    if (base + 3 < N) t += cnt[base + 3];
  }
  t = wredi64(t);
  if (lane == 0) wsum[wid] = t;
  __syncthreads();
  if (tid == 0) bsum[blockIdx.x] = wsum[0] + wsum[1] + wsum[2] + wsum[3];
}

// ---- CSR 2b: exclusive scan of chunk sums (nb <= 1024); also offs[N]=E ----
__global__ void __launch_bounds__(1024)
k_scanB(int* __restrict__ bsum, int* __restrict__ offs, int nb, int E, int N) {
  __shared__ int wsum[16];
  int tid = threadIdx.x, lane = tid & 63, wid = tid >> 6;
  int v = (tid < nb) ? bsum[tid] : 0;
  int x = wscani(v, lane);
  if (lane == 63) wsum[wid] = x;
  __syncthreads();
  if (wid == 0) {
    int w = (lane < 16) ? wsum[lane] : 0;
    w = wscani(w, lane);
    if (lane < 16) wsum[lane] = w;
  }
  __syncthreads();
  int incl = x + (wid ? wsum[wid - 1] : 0);
  if (tid < nb) bsum[tid] = incl - v;   // exclusive
  if (tid == 0) offs[N] = E;
}

// ---- CSR 2c: chunk-local exclusive scan + chunk base -> offs, cur ----
__global__ void __launch_bounds__(256)
k_scanC(const int* __restrict__ cnt, const int* __restrict__ bsum,
        int* __restrict__ offs, int* __restrict__ cur, int N) {
  __shared__ int wsum[4];
  int tid = threadIdx.x, lane = tid & 63, wid = tid >> 6;
  int base = blockIdx.x * 1024 + tid * 4;
  int v0 = 0, v1 = 0, v2 = 0, v3 = 0;
  if (base + 3 < N) {
    int4 q = *(const int4*)(cnt + base);
    v0 = q.x; v1 = q.y; v2 = q.z; v3 = q.w;
  } else {
    if (base < N) v0 = cnt[base];
    if (base + 1 < N) v1 = cnt[base + 1];
    if (base + 2 < N) v2 = cnt[base + 2];
    if (base + 3 < N) v3 = cnt[base + 3];
  }
  int t = v0 + v1 + v2 + v3;
  int incl = wscani(t, lane);
  int exclT = incl - t;
  if (lane == 63) wsum[wid] = incl;
  __syncthreads();
  int wb = 0;
  if (wid > 0) wb += wsum[0];
  if (wid > 1) wb += wsum[1];
  if (wid > 2) wb += wsum[2];
  int eb = bsum[blockIdx.x] + wb + exclT;
  if (base < N)     { offs[base] = eb;           cur[base] = eb; }
  if (base + 1 < N) { int u = eb + v0;           offs[base + 1] = u; cur[base + 1] = u; }
  if (base + 2 < N) { int u = eb + v0 + v1;      offs[base + 2] = u; cur[base + 2] = u; }
  if (base + 3 < N) { int u = eb + v0 + v1 + v2; offs[base + 3] = u; cur[base + 3] = u; }
}

// ---- CSR 3: fill dst-sorted records for BOTH layers.
//  edg1[j] = (x0[s], x1[s], t1, 0)  float4  -> layer-1 gather is pure stream
//  edg2[j] = (s, -, t2, mask)       int4    -> layer-2 (refilled later)
//  where t1 = x[s].(W1sel@as) + ea.(We_sel@ae);  t2 = ea.(We2_sel@ae) ----
__global__ void __launch_bounds__(256)
k_fill(const int* __restrict__ ei, const float* __restrict__ eattr,
       const float* __restrict__ x, const int* __restrict__ mask,
       const float* __restrict__ ae2, const float* __restrict__ l1c,
       int* __restrict__ cur, float4* __restrict__ edg1,
       int4* __restrict__ edg2, int E) {
  int e = blockIdx.x * blockDim.x + threadIdx.x;
  if (e >= E) return;
  int s = ei[e], d = ei[E + e];
  int m = mask[d];
  float2 ea = ((const float2*)eattr)[e];
  float2 xs = ((const float2*)x)[s];     // 8B gather from 800KB (L2-hot)
  const float* lc = l1c + 4 * m;
  float t1 = xs.x * lc[0] + xs.y * lc[1]
           + ea.x * (m ? ae2[2] : ae2[0]) + ea.y * (m ? ae2[3] : ae2[1]);
  float t2 = ea.x * (m ? ae2[6] : ae2[4]) + ea.y * (m ? ae2[7] : ae2[5]);
  int j = atomicAdd(&cur[d], 1);
  edg1[j] = make_float4(xs.x, xs.y, t1, 0.f);
  edg2[j] = make_int4(s, 0, __float_as_int(t2), m);
}

// ---- layer 1 GAT, streaming (x@W commuted past aggregation):
//  y = sum_e ex_e * x[src_e]  (2-dim!), out = (y/den)@W_sel + b_sel.
//  Wave per dst, lane-per-edge, fully coalesced 16B record loads. ----
__global__ void __launch_bounds__(256)
k_gat1(const int* __restrict__ offs, const float4* __restrict__ edg1,
       const float* __restrict__ x, const int* __restrict__ mask,
       const float* __restrict__ l1c, const float* __restrict__ ae2,
       const float* __restrict__ eacc, float invE,
       const float* __restrict__ WL, const float* __restrict__ WG,
       const float* __restrict__ bL, const float* __restrict__ bG,
       float* __restrict__ C, int N) {
  int idx = blockIdx.x * blockDim.x + threadIdx.x;
  int n = idx >> 6, lane = idx & 63;
  if (n >= N) return;
  int m = mask[n];
  float2 xd = ((const float2*)x)[n];
  const float* lc = l1c + 4 * m;
  float as1 = xd.x * lc[0] + xd.y * lc[1];
  float ad  = xd.x * lc[2] + xd.y * lc[3];
  float k0 = m ? ae2[2] : ae2[0];
  float k1 = m ? ae2[3] : ae2[1];
  // self loop (lane-uniform; added once after the butterfly)
  float lg = as1 + ad + (eacc[0] * invE) * k0 + (eacc[1] * invE) * k1;
  lg = lg >= 0.f ? lg : NEG_GAT * lg;
  float es = __expf(lg);
  float y0 = 0.f, y1 = 0.f, den = 0.f;
  int beg = offs[n], end = offs[n + 1];
  for (int j = beg + lane; j < end; j += 64) {
    float4 r = edg1[j];
    float l = r.z + ad;
    l = l >= 0.f ? l : NEG_GAT * l;
    float e = __expf(l);
    y0 = fmaf(e, r.x, y0);
    y1 = fmaf(e, r.y, y1);
    den += e;
  }
  #pragma unroll
  for (int o = 1; o < 64; o <<= 1) {   // butterfly: totals in ALL lanes
    y0 += __shfl_xor(y0, o);
    y1 += __shfl_xor(y1, o);
    den += __shfl_xor(den, o);
  }
  y0 += es * xd.x; y1 += es * xd.y; den += es;
  float inv = 1.f / den;
  const float* W = m ? WG : WL;
  float outv = (y0 * W[lane] + y1 * W[64 + lane]) * inv
             + (m ? bG : bL)[lane];
  C[(size_t)n * 64 + lane] = outv;
}

// ---- BN stats: per-column sum & sumsq over C ----
__global__ void __launch_bounds__(256)
k_bnstat(const float* __restrict__ C, float* sums, float* sq, int N) {
  __shared__ float ls[256], lq[256];
  int col = threadIdx.x & 63, rg = threadIdx.x >> 6;
  float s = 0.f, q = 0.f;
  for (int r = blockIdx.x * 4 + rg; r < N; r += gridDim.x * 4) {
    float v = C[(size_t)r * 64 + col];
    s += v; q += v * v;
  }
  ls[threadIdx.x] = s; lq[threadIdx.x] = q;
  __syncthreads();
  if (rg == 0) {
    s = ls[col] + ls[col + 64] + ls[col + 128] + ls[col + 192];
    q = lq[col] + lq[col + 64] + lq[col + 128] + lq[col + 192];
    atomicAdd(&sums[col], s);
    atomicAdd(&sq[col], q);
  }
}

// ---- BN+leaky in place (C <- c), plus layer-2 alphas = c.(W2@a) ----
__global__ void __launch_bounds__(256)
k_bnact(float* __restrict__ C,
        const float* __restrict__ sums, const float* __restrict__ sq,
        const float* __restrict__ g, const float* __restrict__ beta,
        const float* __restrict__ was2,
        float* asL, float* adL, float* asG, float* adG, int N) {
  int idx = blockIdx.x * blockDim.x + threadIdx.x;
  int n = idx >> 6, lane = idx & 63;
  if (n >= N) return;
  float invN = 1.0f / (float)N;
  float mu = sums[lane] * invN;                  // col == lane
  float var = sq[lane] * invN - mu * mu;
  float v = C[(size_t)n * 64 + lane];
  v = (v - mu) * rsqrtf(var + BN_EPS) * g[lane] + beta[lane];
  float c = v >= 0.f ? v : NEG_ACT * v;
  float d0 = wred64(c * was2[lane]);         // c . (WL2@as2)
  float d1 = wred64(c * was2[64 + lane]);    // c . (WL2@ad2)
  float d2 = wred64(c * was2[128 + lane]);   // c . (WG2@as2)
  float d3 = wred64(c * was2[192 + lane]);   // c . (WG2@ad2)
  if (lane == 0) { asL[n] = d0; adL[n] = d1; asG[n] = d2; adG[n] = d3; }
  C[(size_t)n * 64 + lane] = c;
}

// ---- refill pass (after k_bnact): .y <- as2[src] + t2 (.z), sel by .w ----
__global__ void __launch_bounds__(256)
k_refill(const float* __restrict__ asL2, const float* __restrict__ asG2,
         int4* __restrict__ edg, int E) {
  int j = blockIdx.x * blockDim.x + threadIdx.x;
  if (j >= E) return;
  int4 v = edg[j];
  float as2 = (v.w ? asG2 : asL2)[v.x];
  edg[j].y = __float_as_int(as2 + __int_as_float(v.z));
}

// ---- layer-2 aggregation of c rows, 4 edges per wave-instruction.
//      Wave = 4 groups x 16 lanes; group g handles edge j+g; lane reads a
//      float4 of the 256B c-row. Tail: index clamped, ex masked to 0.
//      Returns normalized y chunk: dims [4*(lane&15) .. +3] in every lane. ----
__device__ __forceinline__ float4 agg_row4(
    int n, int lane, int m,
    const int* __restrict__ offs, const int4* __restrict__ edg,
    const float4* __restrict__ c4,
    const float* __restrict__ asL, const float* __restrict__ adL,
    const float* __restrict__ asG, const float* __restrict__ adG,
    const float* __restrict__ ae2, const float* __restrict__ eacc, float invE) {
  float as_s = (m ? asG : asL)[n];
  float ad   = (m ? adG : adL)[n];
  float k0 = m ? ae2[2] : ae2[0];
  float k1 = m ? ae2[3] : ae2[1];
  int sub = lane & 15, grp = lane >> 4;
  // self loop (ea = column means); counted in group 0 only
  float lg = as_s + ad + (eacc[0] * invE) * k0 + (eacc[1] * invE) * k1;
  lg = lg >= 0.f ? lg : NEG_GAT * lg;
  float exs = __expf(lg);
  float4 hs = c4[(size_t)n * 16 + sub];
  float w = (grp == 0) ? exs : 0.f;
  float ax = w * hs.x, ay = w * hs.y, az = w * hs.z, aw = w * hs.w;
  float denom = w;
  int j = offs[n], end = offs[n + 1];
  for (; j < end; j += 8) {
    int i0 = j + grp, i1 = j + 4 + grp;
    int c0 = i0 < end ? i0 : end - 1;
    int c1 = i1 < end ? i1 : end - 1;
    int4 r0 = edg[(size_t)c0];
    int4 r1 = edg[(size_t)c1];
    float4 h0 = c4[(size_t)r0.x * 16 + sub];
    float4 h1 = c4[(size_t)r1.x * 16 + sub];
    float l0 = __int_as_float(r0.y) + ad;
    float l1 = __int_as_float(r1.y) + ad;
    l0 = l0 >= 0.f ? l0 : NEG_GAT * l0;
    l1 = l1 >= 0.f ? l1 : NEG_GAT * l1;
    float e0 = (i0 < end) ? __expf(l0) : 0.f;
    float e1 = (i1 < end) ? __expf(l1) : 0.f;
    denom += e0 + e1;
    ax = fmaf(e0, h0.x, ax); ay = fmaf(e0, h0.y, ay);
    az = fmaf(e0, h0.z, az); aw = fmaf(e0, h0.w, aw);
    ax = fmaf(e1, h1.x, ax); ay = fmaf(e1, h1.y, ay);
    az = fmaf(e1, h1.z, az); aw = fmaf(e1, h1.w, aw);
  }
  #pragma unroll
  for (int off = 16; off < 64; off <<= 1) {   // combine 4 group-partials
    ax += __shfl_xor(ax, off); ay += __shfl_xor(ay, off);
    az += __shfl_xor(az, off); aw += __shfl_xor(aw, off);
    denom += __shfl_xor(denom, off);
  }
  float inv = 1.f / denom;
  return make_float4(ax * inv, ay * inv, az * inv, aw * inv);
}

// ---- layer 2: aggregate c -> @W2_sel -> +b, leaky -> MLP -> mask -> out ----
__global__ void __launch_bounds__(256)
k_gat2_mlp(const int* __restrict__ offs, const int4* __restrict__ edg,
           const int* __restrict__ mask, const float* __restrict__ C,
           const float* __restrict__ asL, const float* __restrict__ adL,
           const float* __restrict__ asG, const float* __restrict__ adG,
           const float* __restrict__ ae2, const float* __restrict__ eacc,
           float invE,
           const float* __restrict__ WL2, const float* __restrict__ WG2,
           const float* __restrict__ bL, const float* __restrict__ bG,
           const float* __restrict__ f1W, const float* __restrict__ f1b,
           const float* __restrict__ f2W, const float* __restrict__ f2b,
           float* __restrict__ out, int N) {
  int idx = blockIdx.x * blockDim.x + threadIdx.x;
  int n = idx >> 6, lane = idx & 63;
  if (n >= N) return;
  int m = mask[n];
  float4 o = agg_row4(n, lane, m, offs, edg, (const float4*)C,
                      asL, adL, asG, adG, ae2, eacc, invE);
  // h2[lane] = sum_k y[k] * W2sel[k*64+lane]; y[k] in comp k&3 of lane k>>2
  const float* W2 = m ? WG2 : WL2;
  float cv[4] = {o.x, o.y, o.z, o.w};
  float h2 = 0.f;
  #pragma unroll
  for (int k = 0; k < 64; k++) {
    float yb = __shfl(cv[k & 3], k >> 2);
    h2 = fmaf(yb, W2[k * 64 + lane], h2);
  }
  float c = h2 + (m ? bG : bL)[lane];
  c = c >= 0.f ? c : NEG_ACT * c;               // post-layer-2 activation
  float acc = 0.f;
  #pragma unroll
  for (int k = 0; k < 64; k++) {
    float cb = __shfl(c, k);
    if (lane < 32) acc = fmaf(cb, f1W[k * 32 + lane], acc);
  }
  float p = 0.f;
  if (lane < 32) {
    float t = acc + f1b[lane];
    t = t >= 0.f ? t : NEG_ACT * t;
    p = t * f2W[lane];
  }
  p = wred64(p);
  if (lane == 0) out[n] = (p + f2b[0]) * (float)m;
}

extern "C" void kernel_launch(void* const* d_in, const int* in_sizes, int n_in,
                              void* d_out, int out_size, void* d_ws, size_t ws_size,
                              hipStream_t stream) {
  const float* x     = (const float*)d_in[0];
  const float* eattr = (const float*)d_in[1];
  const int*   ei    = (const int*)d_in[2];
  const int*   mask  = (const int*)d_in[3];
  const float* gcn_W  = (const float*)d_in[4];
  const float* gcn_We = (const float*)d_in[5];
  const float* gcn_as = (const float*)d_in[6];
  const float* gcn_ad = (const float*)d_in[7];
  const float* gcn_ae = (const float*)d_in[8];
  const float* gcn_b  = (const float*)d_in[9];
  const float* lit_W  = (const float*)d_in[10];
  const float* lit_We = (const float*)d_in[11];
  const float* lit_as = (const float*)d_in[12];
  const float* lit_ad = (const float*)d_in[13];
  const float* lit_ae = (const float*)d_in[14];
  const float* lit_b  = (const float*)d_in[15];
  const float* gcn2_W  = (const float*)d_in[16];
  const float* gcn2_We = (const float*)d_in[17];
  const float* gcn2_as = (const float*)d_in[18];
  const float* gcn2_ad = (const float*)d_in[19];
  const float* gcn2_ae = (const float*)d_in[20];
  const float* gcn2_b  = (const float*)d_in[21];
  const float* lit2_W  = (const float*)d_in[22];
  const float* lit2_We = (const float*)d_in[23];
  const float* lit2_as = (const float*)d_in[24];
  const float* lit2_ad = (const float*)d_in[25];
  const float* lit2_ae = (const float*)d_in[26];
  const float* lit2_b  = (const float*)d_in[27];
  const float* ln_g    = (const float*)d_in[28];
  const float* ln_beta = (const float*)d_in[29];
  const float* f1W = (const float*)d_in[30];
  const float* f1b = (const float*)d_in[31];
  const float* f2W = (const float*)d_in[32];
  const float* f2b = (const float*)d_in[33];

  const int N = in_sizes[3];
  const int E = in_sizes[1] / 2;
  const size_t N64 = (size_t)N * 64;

  // ---- workspace layout (4-byte units); records first for 16B alignment ----
  float4* edg1 = (float4*)d_ws;            // E  (x0, x1, t1, 0)
  int4*   edg2 = (int4*)(edg1 + E);        // E  (src, y, t2, mask)
  float*  C    = (float*)(edg2 + E);       // N*64 (layer-1 out, then c)
  int*    cnt  = (int*)(C + N64);          // N   [memset region start]
  float*  sums = (float*)(cnt + N);        // 64
  float*  sq   = sums + 64;                // 64
  float*  eacc = sq + 64;                  // 2   [memset region end]
  float*  ae2  = eacc + 2;                 // 8
  float*  l1c  = ae2 + 8;                  // 8
  float*  was2 = l1c + 8;                  // 256
  int*    offs = (int*)(was2 + 256);       // N+1
  int*    cur  = offs + N + 1;             // N
  int*    bsum = cur + N;                  // <=1024
  float*  asL2 = (float*)(bsum + 1024);    // N
  float*  adL2 = asL2 + N;                 // N
  float*  asG2 = adL2 + N;                 // N
  float*  adG2 = asG2 + N;                 // N

  const float invE = 1.0f / (float)E;
  const int TB = 256;
  const int nodeBlocks = (int)((N64 + TB - 1) / TB);   // wave-per-node kernels
  const int eBlocks = (E + TB - 1) / TB;               // thread-per-edge kernels
  const int nb = (N + 1023) / 1024;                    // scan chunks

  // zero cnt, sums, sq, eacc (contiguous)
  hipMemsetAsync(cnt, 0, ((size_t)N + 130) * sizeof(float), stream);

  // ---- constants + CSR build (graph shared by both layers) ----
  k_prep<<<1, 64, 0, stream>>>(lit_W, lit_We, lit_as, lit_ad, lit_ae,
                               gcn_W, gcn_We, gcn_as, gcn_ad, gcn_ae,
                               lit2_W, lit2_We, lit2_as, lit2_ad, lit2_ae,
                               gcn2_W, gcn2_We, gcn2_as, gcn2_ad, gcn2_ae,
                               ae2, l1c, was2);
  k_eamean<<<1024, TB, 0, stream>>>(eattr, eacc, E);
  k_hist<<<eBlocks, TB, 0, stream>>>(ei, cnt, E);
  k_scanA<<<nb, TB, 0, stream>>>(cnt, bsum, N);
  k_scanB<<<1, 1024, 0, stream>>>(bsum, offs, nb, E, N);
  k_scanC<<<nb, TB, 0, stream>>>(cnt, bsum, offs, cur, N);
  k_fill<<<eBlocks, TB, 0, stream>>>(ei, eattr, x, mask, ae2, l1c,
                                     cur, edg1, edg2, E);
  // ---- layer 1 (streaming: x-aggregation, then @W1_sel per dst) ----
  k_gat1<<<nodeBlocks, TB, 0, stream>>>(offs, edg1, x, mask, l1c, ae2,
                                        eacc, invE, lit_W, gcn_W,
                                        lit_b, gcn_b, C, N);
  // ---- BN stats, then BN+leaky in place + layer-2 alphas ----
  k_bnstat<<<384, TB, 0, stream>>>(C, sums, sq, N);
  k_bnact<<<nodeBlocks, TB, 0, stream>>>(C, sums, sq, ln_g, ln_beta, was2,
                                         asL2, adL2, asG2, adG2, N);
  // ---- layer 2: refill records, aggregate c, @W2_sel + MLP ----
  k_refill<<<eBlocks, TB, 0, stream>>>(asL2, asG2, edg2, E);
  k_gat2_mlp<<<nodeBlocks, TB, 0, stream>>>(offs, edg2, mask, C,
                                            asL2, adL2, asG2, adG2,
                                            ae2 + 4, eacc, invE,
                                            lit2_W, gcn2_W, lit2_b, gcn2_b,
                                            f1W, f1b, f2W, f2b,
                                            (float*)d_out, N);
}